// Round 6
// baseline (28.395 us; speedup 1.0000x reference)
//
#include <hip/hip_runtime.h>

#define MAXF 4096
#define CG 8          // channels per block

typedef float f32x4 __attribute__((ext_vector_type(4)));
typedef int   i32x4 __attribute__((ext_vector_type(4)));

// ---------------------------------------------------------------------------
// Fused: per block = (batch b, channel-group of CG), with XCD-aware swizzle
// so that each XCD owns 2 whole batches (xs slab 2 MB fits its 4 MB L2;
// ds/notepitch rows fetched once per XCD instead of 64x).
//  1. wave-shfl scan of ds[b,:] (6 shfl steps + 8-wavesum combine, 2 barriers)
//  2. scatter-build idx table in LDS (== searchsorted(cum, pos, 'right'));
//     only tail [total, MAXF) needs the -1 init
//  3. gather CG channels; idx quad reused in registers; plain float4 stores
//     (nontemporal REGRESSED: r4 32.0 vs r2 28.8 — keep normal L2 write path)
//  4. cg==0 block also writes pitch + total
// ---------------------------------------------------------------------------
__global__ __launch_bounds__(512) void lr_fused(
    const float* __restrict__ xs,         // (B, C, T)
    const float* __restrict__ notepitch,  // (B, T)
    const int* __restrict__ ds,           // (B, T)
    float* __restrict__ out,              // (B, C, MAXF)
    float* __restrict__ pitch_out,        // (B, MAXF)
    float* __restrict__ total_out,        // (B,) as float
    int T, int C)
{
    // ---- XCD-aware block swizzle (nwg % 8 == 0 -> simple chunked form) ----
    const int nwg = gridDim.x;
    int swz = blockIdx.x;
    if ((nwg & 7) == 0) {
        const int cpx = nwg >> 3;
        swz = (swz & 7) * cpx + (swz >> 3);
    }
    const int ncg = C / CG;
    const int b   = swz / ncg;
    const int cg  = swz % ncg;

    const int t    = threadIdx.x;
    const int lane = t & 63;
    const int wid  = t >> 6;      // 0..7

    __shared__ int wsum[8];
    __shared__ int idx_sh[MAXF];

    // ---- wave-level inclusive scan of ds ----
    int v = (t < T) ? ds[b * T + t] : 0;
    int s = v;
#pragma unroll
    for (int off = 1; off < 64; off <<= 1) {
        int y = __shfl_up(s, off, 64);
        if (lane >= off) s += y;
    }
    if (lane == 63) wsum[wid] = s;
    __syncthreads();

    int woff = 0, total = 0;
#pragma unroll
    for (int w = 0; w < 8; ++w) {
        int ws = wsum[w];
        woff  += (w < wid) ? ws : 0;
        total += ws;
    }
    int cum = s + woff;           // inclusive cumsum at position t

    if (total == 0) {             // row_zero: ds -> all ones
        cum = t + 1;
        v = 1;
        total = T;
    }

    // ---- scatter: positions [cum-v, cum) <- t ----
    if (t < T && v > 0) {
        int hi = (cum < MAXF) ? cum : MAXF;
        for (int p = cum - v; p < hi; ++p) idx_sh[p] = t;
    }
    // tail: positions >= total are masked
    for (int p = total + t; p < MAXF; p += 512) idx_sh[p] = -1;
    __syncthreads();

    // ---- gather + write ----
    const float* __restrict__ xbase = xs  + ((size_t)b * C + (size_t)cg * CG) * T;
    float* __restrict__       obase = out + ((size_t)b * C + (size_t)cg * CG) * MAXF;

#pragma unroll
    for (int i = 0; i < MAXF / (512 * 4); ++i) {   // 2 iterations
        const int p4 = (i * 512 + t) * 4;
        i32x4 id = *reinterpret_cast<const i32x4*>(&idx_sh[p4]);
#pragma unroll
        for (int ch = 0; ch < CG; ++ch) {
            const float* __restrict__ xrow = xbase + (size_t)ch * T;
            f32x4 vv;
            vv.x = (id.x >= 0) ? xrow[id.x] : 0.0f;
            vv.y = (id.y >= 0) ? xrow[id.y] : 0.0f;
            vv.z = (id.z >= 0) ? xrow[id.z] : 0.0f;
            vv.w = (id.w >= 0) ? xrow[id.w] : 0.0f;
            *reinterpret_cast<f32x4*>(obase + (size_t)ch * MAXF + p4) = vv;
        }
    }

    if (cg == 0) {
        for (int p = t; p < MAXF; p += 512) {
            int id = idx_sh[p];
            pitch_out[(size_t)b * MAXF + p] = (id >= 0) ? notepitch[b * T + id] : 0.0f;
        }
        if (t == 0) total_out[b] = (float)total;
    }
}

extern "C" void kernel_launch(void* const* d_in, const int* in_sizes, int n_in,
                              void* d_out, int out_size, void* d_ws, size_t ws_size,
                              hipStream_t stream) {
    const float* xs        = (const float*)d_in[0];
    const float* notepitch = (const float*)d_in[1];
    const int*   ds        = (const int*)d_in[2];
    // d_in[3] = x_lengths: unused by the reference computation

    const int B = in_sizes[3];
    const int T = in_sizes[1] / B;
    const int C = in_sizes[0] / (B * T);

    float* out       = (float*)d_out;
    float* pitch_out = out + (size_t)B * C * MAXF;
    float* total_out = pitch_out + (size_t)B * MAXF;

    lr_fused<<<B * (C / CG), 512, 0, stream>>>(xs, notepitch, ds, out, pitch_out, total_out, T, C);
}

// Round 7
// 26.248 us; speedup vs baseline: 1.0818x; 1.0818x over previous
//
#include <hip/hip_runtime.h>

#define MAXF 4096
#define CG 8          // channels per block

typedef float f32x4 __attribute__((ext_vector_type(4)));
typedef int   i32x4 __attribute__((ext_vector_type(4)));

// ---------------------------------------------------------------------------
// Fused, LDS-gather version. Per block = (batch b, channel-group of CG).
//  0. issue coalesced loads of the 16KB xs tile (latency hides under scan)
//  1. wave-shfl scan of ds[b,:] (6 shfl steps + 8-wavesum combine)
//  2. stage xs tile into LDS; scatter-build idx table in LDS
//     (== searchsorted(cum, pos, 'right')); tail [total,MAXF) = -1
//  3. gather from LDS (clustered idx -> broadcast/2-way, ~free) so the VMEM
//     path carries ONLY coalesced float4 stores (scattered global gather
//     loads cost ~16cy/wave of TA address processing each)
//  4. cg==0 block also writes pitch + total
// notes: nontemporal stores REGRESSED (r4); XCD swizzle NEUTRAL (r6).
// ---------------------------------------------------------------------------
__global__ __launch_bounds__(512) void lr_fused(
    const float* __restrict__ xs,         // (B, C, T)
    const float* __restrict__ notepitch,  // (B, T)
    const int* __restrict__ ds,           // (B, T)
    float* __restrict__ out,              // (B, C, MAXF)
    float* __restrict__ pitch_out,        // (B, MAXF)
    float* __restrict__ total_out,        // (B,) as float
    int T, int C)
{
    const int b  = blockIdx.y;
    const int cg = blockIdx.x;
    const int t  = threadIdx.x;
    const int lane = t & 63;
    const int wid  = t >> 6;      // 0..7

    __shared__ float xtile[CG * 512];   // 16KB
    __shared__ int   idx_sh[MAXF];      // 16KB
    __shared__ int   wsum[8];

    // ---- 0. issue xs tile loads (contiguous 16KB: CG consecutive rows) ----
    const float* __restrict__ xbase = xs + ((size_t)b * C + (size_t)cg * CG) * T;
    f32x4 st0 = *reinterpret_cast<const f32x4*>(xbase + t * 4);
    f32x4 st1 = *reinterpret_cast<const f32x4*>(xbase + 2048 + t * 4);

    // ---- 1. wave-level inclusive scan of ds ----
    int v = (t < T) ? ds[b * T + t] : 0;
    int s = v;
#pragma unroll
    for (int off = 1; off < 64; off <<= 1) {
        int y = __shfl_up(s, off, 64);
        if (lane >= off) s += y;
    }
    if (lane == 63) wsum[wid] = s;
    __syncthreads();

    int woff = 0, total = 0;
#pragma unroll
    for (int w = 0; w < 8; ++w) {
        int ws = wsum[w];
        woff  += (w < wid) ? ws : 0;
        total += ws;
    }
    int cum = s + woff;           // inclusive cumsum at position t

    if (total == 0) {             // row_zero: ds -> all ones
        cum = t + 1;
        v = 1;
        total = T;
    }

    // ---- 2. stage xs tile; scatter idx; tail init ----
    *reinterpret_cast<f32x4*>(&xtile[t * 4])        = st0;
    *reinterpret_cast<f32x4*>(&xtile[2048 + t * 4]) = st1;

    if (t < T && v > 0) {
        int hi = (cum < MAXF) ? cum : MAXF;
        for (int p = cum - v; p < hi; ++p) idx_sh[p] = t;
    }
    for (int p = total + t; p < MAXF; p += 512) idx_sh[p] = -1;
    __syncthreads();

    // ---- 3. gather from LDS + coalesced global stores ----
    float* __restrict__ obase = out + ((size_t)b * C + (size_t)cg * CG) * MAXF;

#pragma unroll
    for (int i = 0; i < MAXF / (512 * 4); ++i) {   // 2 iterations
        const int p4 = (i * 512 + t) * 4;
        i32x4 id = *reinterpret_cast<const i32x4*>(&idx_sh[p4]);
        const int jx = (id.x >= 0) ? id.x : 0;
        const int jy = (id.y >= 0) ? id.y : 0;
        const int jz = (id.z >= 0) ? id.z : 0;
        const int jw = (id.w >= 0) ? id.w : 0;
#pragma unroll
        for (int ch = 0; ch < CG; ++ch) {
            const float* __restrict__ xrow = &xtile[ch * 512];
            f32x4 vv;
            vv.x = (id.x >= 0) ? xrow[jx] : 0.0f;
            vv.y = (id.y >= 0) ? xrow[jy] : 0.0f;
            vv.z = (id.z >= 0) ? xrow[jz] : 0.0f;
            vv.w = (id.w >= 0) ? xrow[jw] : 0.0f;
            *reinterpret_cast<f32x4*>(obase + (size_t)ch * MAXF + p4) = vv;
        }
    }

    // ---- 4. pitch + total (one channel-group per batch) ----
    if (cg == 0) {
        for (int p = t; p < MAXF; p += 512) {
            int id = idx_sh[p];
            pitch_out[(size_t)b * MAXF + p] = (id >= 0) ? notepitch[b * T + id] : 0.0f;
        }
        if (t == 0) total_out[b] = (float)total;
    }
}

extern "C" void kernel_launch(void* const* d_in, const int* in_sizes, int n_in,
                              void* d_out, int out_size, void* d_ws, size_t ws_size,
                              hipStream_t stream) {
    const float* xs        = (const float*)d_in[0];
    const float* notepitch = (const float*)d_in[1];
    const int*   ds        = (const int*)d_in[2];
    // d_in[3] = x_lengths: unused by the reference computation

    const int B = in_sizes[3];
    const int T = in_sizes[1] / B;
    const int C = in_sizes[0] / (B * T);

    float* out       = (float*)d_out;
    float* pitch_out = out + (size_t)B * C * MAXF;
    float* total_out = pitch_out + (size_t)B * MAXF;

    dim3 grid(C / CG, B);
    lr_fused<<<grid, 512, 0, stream>>>(xs, notepitch, ds, out, pitch_out, total_out, T, C);
}